// Round 9
// baseline (111.524 us; speedup 1.0000x reference)
//
#include <hip/hip_runtime.h>
#include <stdint.h>

// Problem constants (fixed by setup_inputs): B=8, C=4, N=16, H=W=256.
constexpr int HW      = 256 * 256;          // 65536 pixels per (b)
constexpr int C       = 4;
constexpr int N       = 16;
constexpr int BATCH   = 8;
constexpr int GROUPS  = BATCH * (HW / 4);   // one thread per 4 pixels = 131072
constexpr int BLOCK   = 256;
constexpr int GRID    = GROUPS / BLOCK;     // 512 blocks = 2 blocks/CU
constexpr float INV_COUNT = 1.0f / 33554432.0f;  // 1 / (B*N*C*H*W)

// Native clang vectors: __builtin_nontemporal_load rejects HIP_vector_type
// structs (round-6 compile error) but accepts ext_vector_type.
typedef float fx4 __attribute__((ext_vector_type(4)));
typedef int   ix4 __attribute__((ext_vector_type(4)));

// Closed-form collapse (masks are 0/1 so m^2 == m):
//   sum_{n,c} (pd_c*pm_n - gt_c*gm_n)^2 = a*P + b*G - 2*ab*X
// with P=sum_c pd_c^2, G=sum_c gt_c^2, X=sum_c pd_c*gt_c,
//      a=sum_n pm_n, b=sum_n gm_n, ab=sum_n pm_n*gm_n.
// One streaming pass: 16.8 MB f32 + 67 MB i32 masks = 84 MB -> ~13.3 us floor.
// Round-2 lesson: harness delivers jax bool as int32 (value-of-0.25 bug).
// Round-3 lesson: dur_us window is dominated by harness re-poison fills
// (~41 us each at ~6.5 TB/s); our kernel is <40 us (absent from top-5).
__global__ __launch_bounds__(BLOCK) void mse_partial_kernel(
    const float* __restrict__ pd, const float* __restrict__ gt,
    const int* __restrict__ pdm, const int* __restrict__ gtm,
    float* __restrict__ partial)
{
    const int g   = blockIdx.x * BLOCK + threadIdx.x;  // [0, 131072)
    const int b   = g >> 14;                           // / (HW/4)
    const int pix = (g & 16383) << 2;                  // first of 4 pixels

    const fx4* pd4 = reinterpret_cast<const fx4*>(pd + (size_t)b * C * HW + pix);
    const fx4* gt4 = reinterpret_cast<const fx4*>(gt + (size_t)b * C * HW + pix);

    // Streamed once, never reused: non-temporal loads keep L2 clean.
    float P[4]  = {0.f, 0.f, 0.f, 0.f};
    float Gs[4] = {0.f, 0.f, 0.f, 0.f};
    float X[4]  = {0.f, 0.f, 0.f, 0.f};
    #pragma unroll
    for (int c = 0; c < C; ++c) {
        fx4 p = __builtin_nontemporal_load(&pd4[c * (HW / 4)]);
        fx4 q = __builtin_nontemporal_load(&gt4[c * (HW / 4)]);
        #pragma unroll
        for (int j = 0; j < 4; ++j) {
            P[j]  = fmaf(p[j], p[j], P[j]);
            Gs[j] = fmaf(q[j], q[j], Gs[j]);
            X[j]  = fmaf(p[j], q[j], X[j]);
        }
    }

    // Mask counts: 16B load covers this thread's 4 pixels for one n.
    const ix4* pmu = reinterpret_cast<const ix4*>(pdm + (size_t)b * N * HW + pix);
    const ix4* gmu = reinterpret_cast<const ix4*>(gtm + (size_t)b * N * HW + pix);
    int ca[4]  = {0, 0, 0, 0};
    int cb[4]  = {0, 0, 0, 0};
    int cab[4] = {0, 0, 0, 0};
    #pragma unroll
    for (int n = 0; n < N; ++n) {
        ix4 am = __builtin_nontemporal_load(&pmu[n * (HW / 4)]);
        ix4 bm = __builtin_nontemporal_load(&gmu[n * (HW / 4)]);
        #pragma unroll
        for (int j = 0; j < 4; ++j) {
            ca[j]  += am[j];
            cb[j]  += bm[j];
            cab[j] += am[j] & bm[j];
        }
    }

    float acc = 0.0f;
    #pragma unroll
    for (int j = 0; j < 4; ++j) {
        acc += (float)ca[j] * P[j] + (float)cb[j] * Gs[j]
             - 2.0f * (float)cab[j] * X[j];
    }

    // Wave(64) shuffle reduce, then cross-wave via LDS.
    #pragma unroll
    for (int off = 32; off > 0; off >>= 1)
        acc += __shfl_down(acc, off, 64);

    __shared__ float sacc[BLOCK / 64];
    const int lane = threadIdx.x & 63;
    const int wave = threadIdx.x >> 6;
    if (lane == 0) sacc[wave] = acc;
    __syncthreads();
    if (threadIdx.x == 0)
        partial[blockIdx.x] = sacc[0] + sacc[1] + sacc[2] + sacc[3];
}

__global__ __launch_bounds__(BLOCK) void mse_final_kernel(
    const float* __restrict__ partial, float* __restrict__ out)
{
    // GRID=512 partials, 256 threads: 2 each.
    float acc = partial[threadIdx.x] + partial[threadIdx.x + BLOCK];
    #pragma unroll
    for (int off = 32; off > 0; off >>= 1)
        acc += __shfl_down(acc, off, 64);

    __shared__ float sacc[BLOCK / 64];
    const int lane = threadIdx.x & 63;
    const int wave = threadIdx.x >> 6;
    if (lane == 0) sacc[wave] = acc;
    __syncthreads();
    if (threadIdx.x == 0)
        out[0] = (sacc[0] + sacc[1] + sacc[2] + sacc[3]) * INV_COUNT;
}

extern "C" void kernel_launch(void* const* d_in, const int* in_sizes, int n_in,
                              void* d_out, int out_size, void* d_ws, size_t ws_size,
                              hipStream_t stream) {
    const float* pd  = (const float*)d_in[0];
    const float* gt  = (const float*)d_in[1];
    const int*   pdm = (const int*)d_in[2];   // jax bool -> int32 per harness
    const int*   gtm = (const int*)d_in[3];
    float* out     = (float*)d_out;
    float* partial = (float*)d_ws;            // 512 floats, all written each call

    mse_partial_kernel<<<GRID, BLOCK, 0, stream>>>(pd, gt, pdm, gtm, partial);
    mse_final_kernel<<<1, BLOCK, 0, stream>>>(partial, out);
}